// Round 6
// baseline (2474.080 us; speedup 1.0000x reference)
//
#include <hip/hip_runtime.h>

// B=64, L=196, CV=2048, T=20 (19 steps), VOCAB=10000, E=H=A=512, 4H=2048
// Round 6 = round 5 + (a) kq fused into attention (per-b GEMV),
//           (b) gemm_emb on MFMA, (c) pre-converted bf16 Wv for gemm_k.

typedef __bf16 bf16x8 __attribute__((ext_vector_type(8)));
typedef float f32x4 __attribute__((ext_vector_type(4)));
typedef unsigned short ushort8 __attribute__((ext_vector_type(8)));

// ---------------- workspace layout (float offsets), ~5.75 MB ----------------
#define OFF_HALL 0ull                   // hall fp32 [19*64][512]  = 622592 f
#define OFF_X2H  622592ull              // x2h bf16 [64][2560]     = 81920 f-equiv
#define OFF_H    704512ull              // h fp32 [64][512]
#define OFF_C    737280ull              // c fp32 [64][512]
#define OFF_QP   770048ull              // (unused this round)
#define OFF_PART 901120ull              // gates split-K partials fp32 [4][64][2048]
#define OFF_AB   1425408ull             // attention weights fp32 [64][196]
// end = 1,437,952 floats

// ---------------- d_out scrap (float offsets; all dead before gemm_logits,
//                  and gemm_logits reads NOTHING from d_out) ----------------
#define D_WGH 0ull                      // Wg bf16 [2048][2560] = 2,621,440 f-equiv
#define D_GE  2621440ull                // gates_emb fp32 [1216][2048] = 2,490,368 f
#define D_KB  5111808ull                // k bf16 [12544][512] = 3,211,264 f-equiv
#define D_WV  8323072ull                // Wv bf16 [512][2048] = 524,288 f-equiv
// end = 8,847,360 <= 12,160,000

__device__ __forceinline__ unsigned short f2bf(float f) {
    unsigned int u = __float_as_uint(f);
    unsigned int r = u + 0x7FFFu + ((u >> 16) & 1u);
    return (unsigned short)(r >> 16);
}
__device__ __forceinline__ float bf2f(unsigned short h) {
    return __uint_as_float(((unsigned int)h) << 16);
}
__device__ __forceinline__ float ftanh(float x) {
    x = fminf(fmaxf(x, -15.f), 15.f);
    float e = __expf(2.f * x);
    return (e - 1.f) / (e + 1.f);
}
__device__ __forceinline__ float fsig(float x) {
    x = fminf(fmaxf(x, -30.f), 30.f);
    return 1.f / (1.f + __expf(-x));
}

// ---------------- init: zero h, c, x2h h-part ----------------
__global__ void init_state(float* __restrict__ ws) {
    const int b = blockIdx.x, tid = threadIdx.x;
    float* h  = ws + OFF_H;
    float* c  = ws + OFF_C;
    unsigned short* x2h = (unsigned short*)(ws + OFF_X2H);
    for (int j = tid; j < 512; j += 256) {
        h[b * 512 + j] = 0.f;
        c[b * 512 + j] = 0.f;
        x2h[b * 2560 + 2048 + j] = 0;
    }
}

// ---------------- Wg bf16 = [Wih[:,512:] | Whh]  [2048][2560] ----------------
__global__ __launch_bounds__(256)
void conv_wg(const float* __restrict__ Wih, const float* __restrict__ Whh,
             unsigned short* __restrict__ Wgh) {
    const int idx = blockIdx.x * 256 + threadIdx.x;   // 2560 blocks, 8 elems each
    const int j = idx / 320;
    const int c0 = (idx - j * 320) * 8;
    const float* src;
    if (c0 < 2048) src = Wih + (size_t)j * 2560 + 512 + c0;
    else           src = Whh + (size_t)j * 512 + (c0 - 2048);
    float4 a = *reinterpret_cast<const float4*>(src);
    float4 b = *reinterpret_cast<const float4*>(src + 4);
    ushort8 o;
    o[0]=f2bf(a.x); o[1]=f2bf(a.y); o[2]=f2bf(a.z); o[3]=f2bf(a.w);
    o[4]=f2bf(b.x); o[5]=f2bf(b.y); o[6]=f2bf(b.z); o[7]=f2bf(b.w);
    *reinterpret_cast<ushort8*>(Wgh + (size_t)j * 2560 + c0) = o;
}

// ---------------- Wv bf16 [512][2048] ----------------
__global__ __launch_bounds__(256)
void conv_wv(const float* __restrict__ Wv, unsigned short* __restrict__ Wvb) {
    const size_t idx = ((size_t)blockIdx.x * 256 + threadIdx.x) * 8;  // 512 blocks
    float4 a = *reinterpret_cast<const float4*>(Wv + idx);
    float4 b = *reinterpret_cast<const float4*>(Wv + idx + 4);
    ushort8 o;
    o[0]=f2bf(a.x); o[1]=f2bf(a.y); o[2]=f2bf(a.z); o[3]=f2bf(a.w);
    o[4]=f2bf(b.x); o[5]=f2bf(b.y); o[6]=f2bf(b.z); o[7]=f2bf(b.w);
    *reinterpret_cast<ushort8*>(Wvb + idx) = o;
}

// ---------------- k = V @ Wv^T + bv  (MFMA bf16; B pre-converted) ----------------
// M=12544 N=512 K=2048, tile 64x64, BK=32, 4 waves (2x2 of 32x32)
__global__ __launch_bounds__(256)
void gemm_k_mfma(const float* __restrict__ V, const unsigned short* __restrict__ Wvb,
                 const float* __restrict__ bv, unsigned short* __restrict__ kout) {
    __shared__ unsigned short At[64 * 32];
    __shared__ unsigned short Bt[64 * 32];
    const int tid = threadIdx.x;
    const int lane = tid & 63, wave = tid >> 6;
    const int wr = wave >> 1, wc = wave & 1;
    const int m0 = blockIdx.x * 64, n0 = blockIdx.y * 64;
    const int srow = tid >> 2, skg = tid & 3;
    const float* ga = V + (size_t)(m0 + srow) * 2048 + skg * 8;
    const unsigned short* gb = Wvb + (size_t)(n0 + srow) * 2048 + skg * 8;
    const int ar0 = (wr * 32 + (lane & 15)) * 32 + (lane >> 4) * 8;
    const int br0 = (wc * 32 + (lane & 15)) * 32 + (lane >> 4) * 8;
    f32x4 acc[2][2] = {};
    for (int k0 = 0; k0 < 2048; k0 += 32) {
        float4 a0 = *reinterpret_cast<const float4*>(ga + k0);
        float4 a1 = *reinterpret_cast<const float4*>(ga + k0 + 4);
        ushort8 ub = *reinterpret_cast<const ushort8*>(gb + k0);
        ushort8 ua;
        ua[0]=f2bf(a0.x); ua[1]=f2bf(a0.y); ua[2]=f2bf(a0.z); ua[3]=f2bf(a0.w);
        ua[4]=f2bf(a1.x); ua[5]=f2bf(a1.y); ua[6]=f2bf(a1.z); ua[7]=f2bf(a1.w);
        *reinterpret_cast<ushort8*>(&At[tid * 8]) = ua;
        *reinterpret_cast<ushort8*>(&Bt[tid * 8]) = ub;
        __syncthreads();
        bf16x8 af0 = *reinterpret_cast<const bf16x8*>(&At[ar0]);
        bf16x8 af1 = *reinterpret_cast<const bf16x8*>(&At[ar0 + 16 * 32]);
        bf16x8 bf0 = *reinterpret_cast<const bf16x8*>(&Bt[br0]);
        bf16x8 bf1 = *reinterpret_cast<const bf16x8*>(&Bt[br0 + 16 * 32]);
        acc[0][0] = __builtin_amdgcn_mfma_f32_16x16x32_bf16(af0, bf0, acc[0][0], 0, 0, 0);
        acc[0][1] = __builtin_amdgcn_mfma_f32_16x16x32_bf16(af0, bf1, acc[0][1], 0, 0, 0);
        acc[1][0] = __builtin_amdgcn_mfma_f32_16x16x32_bf16(af1, bf0, acc[1][0], 0, 0, 0);
        acc[1][1] = __builtin_amdgcn_mfma_f32_16x16x32_bf16(af1, bf1, acc[1][1], 0, 0, 0);
        __syncthreads();
    }
#pragma unroll
    for (int fi = 0; fi < 2; ++fi)
#pragma unroll
        for (int fj = 0; fj < 2; ++fj)
#pragma unroll
            for (int r = 0; r < 4; ++r) {
                int m = m0 + wr * 32 + fi * 16 + (lane >> 4) * 4 + r;
                int n = n0 + wc * 32 + fj * 16 + (lane & 15);
                kout[(size_t)m * 512 + n] = f2bf(acc[fi][fj][r] + bv[n]);
            }
}

// ------- gates_emb via MFMA: ge[t,b,:] = embed[caps[b,t]] @ Wih[:,:512]^T + bih + bhh -------
// per t: M=64(batch) N=2048(gates) K=512; grid (19, 32); tile 64x64
__global__ __launch_bounds__(256)
void emb_mfma(const float* __restrict__ embW, const int* __restrict__ caps,
              const float* __restrict__ Wih, const float* __restrict__ bih,
              const float* __restrict__ bhh, float* __restrict__ ge) {
    __shared__ unsigned short At[64 * 32];
    __shared__ unsigned short Bt[64 * 32];
    const int t = blockIdx.x;
    const int n0 = blockIdx.y * 64;
    const int tid = threadIdx.x;
    const int lane = tid & 63, wave = tid >> 6;
    const int wr = wave >> 1, wc = wave & 1;
    const int srow = tid >> 2, skg = tid & 3;
    const int cap = caps[srow * 20 + t];              // A-row gather
    const float* ga = embW + (size_t)cap * 512 + skg * 8;
    const float* gb = Wih + (size_t)(n0 + srow) * 2560 + skg * 8;  // first 512 cols
    const int ar0 = (wr * 32 + (lane & 15)) * 32 + (lane >> 4) * 8;
    const int br0 = (wc * 32 + (lane & 15)) * 32 + (lane >> 4) * 8;
    f32x4 acc[2][2] = {};
    for (int k0 = 0; k0 < 512; k0 += 32) {
        float4 a0 = *reinterpret_cast<const float4*>(ga + k0);
        float4 a1 = *reinterpret_cast<const float4*>(ga + k0 + 4);
        float4 b0 = *reinterpret_cast<const float4*>(gb + k0);
        float4 b1 = *reinterpret_cast<const float4*>(gb + k0 + 4);
        ushort8 ua, ub;
        ua[0]=f2bf(a0.x); ua[1]=f2bf(a0.y); ua[2]=f2bf(a0.z); ua[3]=f2bf(a0.w);
        ua[4]=f2bf(a1.x); ua[5]=f2bf(a1.y); ua[6]=f2bf(a1.z); ua[7]=f2bf(a1.w);
        ub[0]=f2bf(b0.x); ub[1]=f2bf(b0.y); ub[2]=f2bf(b0.z); ub[3]=f2bf(b0.w);
        ub[4]=f2bf(b1.x); ub[5]=f2bf(b1.y); ub[6]=f2bf(b1.z); ub[7]=f2bf(b1.w);
        *reinterpret_cast<ushort8*>(&At[tid * 8]) = ua;
        *reinterpret_cast<ushort8*>(&Bt[tid * 8]) = ub;
        __syncthreads();
        bf16x8 af0 = *reinterpret_cast<const bf16x8*>(&At[ar0]);
        bf16x8 af1 = *reinterpret_cast<const bf16x8*>(&At[ar0 + 16 * 32]);
        bf16x8 bf0 = *reinterpret_cast<const bf16x8*>(&Bt[br0]);
        bf16x8 bf1 = *reinterpret_cast<const bf16x8*>(&Bt[br0 + 16 * 32]);
        acc[0][0] = __builtin_amdgcn_mfma_f32_16x16x32_bf16(af0, bf0, acc[0][0], 0, 0, 0);
        acc[0][1] = __builtin_amdgcn_mfma_f32_16x16x32_bf16(af0, bf1, acc[0][1], 0, 0, 0);
        acc[1][0] = __builtin_amdgcn_mfma_f32_16x16x32_bf16(af1, bf0, acc[1][0], 0, 0, 0);
        acc[1][1] = __builtin_amdgcn_mfma_f32_16x16x32_bf16(af1, bf1, acc[1][1], 0, 0, 0);
        __syncthreads();
    }
#pragma unroll
    for (int fi = 0; fi < 2; ++fi)
#pragma unroll
        for (int fj = 0; fj < 2; ++fj)
#pragma unroll
            for (int r = 0; r < 4; ++r) {
                int m = wr * 32 + fi * 16 + (lane >> 4) * 4 + r;   // batch row
                int n = n0 + wc * 32 + fj * 16 + (lane & 15);      // gate col
                ge[(size_t)(t * 64 + m) * 2048 + n] = acc[fi][fj][r] + bih[n] + bhh[n];
            }
}

// ------- fused q-GEMV + attention softmax -> abuf (one block per batch) -------
__global__ __launch_bounds__(256)
void attn_fused(const float* __restrict__ Whw, const float* __restrict__ Whb,
                const float* __restrict__ vw, const unsigned short* __restrict__ kb,
                float* __restrict__ ws) {
    const int b = blockIdx.x, tid = threadIdx.x;
    const int lane = tid & 63, w = tid >> 6;
    const float* h = ws + OFF_H + b * 512;
    float* abuf = ws + OFF_AB;
    __shared__ float qs[512];
    __shared__ float es[196];
    __shared__ float red[256];
    float hr[8];
    {
        float4 h0 = *reinterpret_cast<const float4*>(h + lane * 8);
        float4 h1 = *reinterpret_cast<const float4*>(h + lane * 8 + 4);
        hr[0]=h0.x; hr[1]=h0.y; hr[2]=h0.z; hr[3]=h0.w;
        hr[4]=h1.x; hr[5]=h1.y; hr[6]=h1.z; hr[7]=h1.w;
    }
    // wave w computes q[j] for j in [w*128, w*128+128)
    for (int j = w * 128; j < w * 128 + 128; j += 2) {
        const float* w0 = Whw + (size_t)j * 512 + lane * 8;
        const float* w1 = w0 + 512;
        float4 a0 = *reinterpret_cast<const float4*>(w0);
        float4 a1 = *reinterpret_cast<const float4*>(w0 + 4);
        float4 b0 = *reinterpret_cast<const float4*>(w1);
        float4 b1 = *reinterpret_cast<const float4*>(w1 + 4);
        float s0 = hr[0]*a0.x + hr[1]*a0.y + hr[2]*a0.z + hr[3]*a0.w
                 + hr[4]*a1.x + hr[5]*a1.y + hr[6]*a1.z + hr[7]*a1.w;
        float s1 = hr[0]*b0.x + hr[1]*b0.y + hr[2]*b0.z + hr[3]*b0.w
                 + hr[4]*b1.x + hr[5]*b1.y + hr[6]*b1.z + hr[7]*b1.w;
#pragma unroll
        for (int mm = 32; mm >= 1; mm >>= 1) {
            s0 += __shfl_xor(s0, mm);
            s1 += __shfl_xor(s1, mm);
        }
        if (lane == 0) {
            qs[j]     = s0 + Whb[j];
            qs[j + 1] = s1 + Whb[j + 1];
        }
    }
    __syncthreads();
    float qr[8], vr[8];
#pragma unroll
    for (int j = 0; j < 8; ++j) {
        qr[j] = qs[lane * 8 + j];
        vr[j] = vw[lane * 8 + j];
    }
    for (int l = w; l < 196; l += 4) {
        const unsigned short* kr = kb + (size_t)(b * 196 + l) * 512 + lane * 8;
        ushort8 kv = *reinterpret_cast<const ushort8*>(kr);
        float s = 0.f;
#pragma unroll
        for (int j = 0; j < 8; ++j)
            s += vr[j] * ftanh(qr[j] + bf2f(kv[j]));
#pragma unroll
        for (int mm = 32; mm >= 1; mm >>= 1) s += __shfl_xor(s, mm);
        if (lane == 0) es[l] = s;
    }
    __syncthreads();
    float ev = (tid < 196) ? es[tid] : -1e30f;
    red[tid] = ev;
    __syncthreads();
    for (int s2 = 128; s2 > 0; s2 >>= 1) {
        if (tid < s2) red[tid] = fmaxf(red[tid], red[tid + s2]);
        __syncthreads();
    }
    float mx = red[0];
    __syncthreads();
    float p = (tid < 196) ? __expf(ev - mx) : 0.f;
    red[tid] = p;
    __syncthreads();
    for (int s2 = 128; s2 > 0; s2 >>= 1) {
        if (tid < s2) red[tid] += red[tid + s2];
        __syncthreads();
    }
    if (tid < 196) abuf[b * 196 + tid] = p / red[0];
}

// ---------------- ctx[b,c] = sum_l a[b,l] V[b,l,c] -> x2h bf16 (512 blocks) ----------------
__global__ __launch_bounds__(256)
void ctx_wide(const float* __restrict__ V, float* __restrict__ ws) {
    const int b = blockIdx.y, tid = threadIdx.x;
    const int c = blockIdx.x * 256 + tid;
    const float* abuf = ws + OFF_AB;
    unsigned short* x2h = (unsigned short*)(ws + OFF_X2H);
    __shared__ float as_[196];
    if (tid < 196) as_[tid] = abuf[b * 196 + tid];
    __syncthreads();
    const float* vb = V + (size_t)b * 196 * 2048 + c;
    float a0 = 0.f, a1 = 0.f, a2 = 0.f, a3 = 0.f;
    for (int l = 0; l < 196; l += 4) {
        a0 = fmaf(as_[l + 0], vb[(size_t)(l + 0) * 2048], a0);
        a1 = fmaf(as_[l + 1], vb[(size_t)(l + 1) * 2048], a1);
        a2 = fmaf(as_[l + 2], vb[(size_t)(l + 2) * 2048], a2);
        a3 = fmaf(as_[l + 3], vb[(size_t)(l + 3) * 2048], a3);
    }
    x2h[(size_t)b * 2560 + c] = f2bf((a0 + a1) + (a2 + a3));
}

// ------- gates partials via MFMA: part[kc] = x2h @ Wgh^T over K-chunk kc -------
__global__ __launch_bounds__(256)
void gates_mfma(const float* __restrict__ ws, const unsigned short* __restrict__ Wgh,
                float* __restrict__ part_out) {
    __shared__ unsigned short At[64 * 32];
    __shared__ unsigned short Bt[64 * 32];
    const unsigned short* x2h = (const unsigned short*)(ws + OFF_X2H);
    const int tid = threadIdx.x;
    const int lane = tid & 63, wave = tid >> 6;
    const int wr = wave >> 1, wc = wave & 1;
    const int n0 = blockIdx.x * 64;
    const int kc = blockIdx.y;
    const int srow = tid >> 2, skg = tid & 3;
    const unsigned short* ga = x2h + (size_t)srow * 2560 + kc * 640 + skg * 8;
    const unsigned short* gb = Wgh + (size_t)(n0 + srow) * 2560 + kc * 640 + skg * 8;
    const int ar0 = (wr * 32 + (lane & 15)) * 32 + (lane >> 4) * 8;
    const int br0 = (wc * 32 + (lane & 15)) * 32 + (lane >> 4) * 8;
    f32x4 acc[2][2] = {};
    for (int kt = 0; kt < 20; ++kt) {
        *reinterpret_cast<ushort8*>(&At[tid * 8]) = *reinterpret_cast<const ushort8*>(ga + kt * 32);
        *reinterpret_cast<ushort8*>(&Bt[tid * 8]) = *reinterpret_cast<const ushort8*>(gb + kt * 32);
        __syncthreads();
        bf16x8 af0 = *reinterpret_cast<const bf16x8*>(&At[ar0]);
        bf16x8 af1 = *reinterpret_cast<const bf16x8*>(&At[ar0 + 16 * 32]);
        bf16x8 bf0 = *reinterpret_cast<const bf16x8*>(&Bt[br0]);
        bf16x8 bf1 = *reinterpret_cast<const bf16x8*>(&Bt[br0 + 16 * 32]);
        acc[0][0] = __builtin_amdgcn_mfma_f32_16x16x32_bf16(af0, bf0, acc[0][0], 0, 0, 0);
        acc[0][1] = __builtin_amdgcn_mfma_f32_16x16x32_bf16(af0, bf1, acc[0][1], 0, 0, 0);
        acc[1][0] = __builtin_amdgcn_mfma_f32_16x16x32_bf16(af1, bf0, acc[1][0], 0, 0, 0);
        acc[1][1] = __builtin_amdgcn_mfma_f32_16x16x32_bf16(af1, bf1, acc[1][1], 0, 0, 0);
        __syncthreads();
    }
#pragma unroll
    for (int fi = 0; fi < 2; ++fi)
#pragma unroll
        for (int fj = 0; fj < 2; ++fj)
#pragma unroll
            for (int r = 0; r < 4; ++r) {
                int m = wr * 32 + fi * 16 + (lane >> 4) * 4 + r;   // batch row
                int n = n0 + wc * 32 + fj * 16 + (lane & 15);      // gate col
                part_out[(size_t)(kc * 64 + m) * 2048 + n] = acc[fi][fj][r];
            }
}

// ---------------- LSTM pointwise: reduce partials + ge -> h,c ----------------
__global__ __launch_bounds__(256)
void lstm_step(float* __restrict__ ws, const float* __restrict__ geb, int t) {
    const int b = blockIdx.x, tid = threadIdx.x;
    const float* ge = geb + (size_t)(t * 64 + b) * 2048;
    const float* part = ws + OFF_PART;
    float* h = ws + OFF_H;
    float* c = ws + OFF_C;
    unsigned short* x2h = (unsigned short*)(ws + OFF_X2H);
    float* hall = ws + OFF_HALL;
#pragma unroll
    for (int jj = 0; jj < 2; ++jj) {
        int j = tid + jj * 256;
        float ig = ge[j], fg = ge[512 + j], gg = ge[1024 + j], og = ge[1536 + j];
#pragma unroll
        for (int p = 0; p < 4; ++p) {
            const float* pp = part + (size_t)(p * 64 + b) * 2048;
            ig += pp[j]; fg += pp[512 + j]; gg += pp[1024 + j]; og += pp[1536 + j];
        }
        float cv = fsig(fg) * c[b * 512 + j] + fsig(ig) * ftanh(gg);
        float hv = fsig(og) * ftanh(cv);
        c[b * 512 + j] = cv;
        h[b * 512 + j] = hv;
        x2h[(size_t)b * 2560 + 2048 + j] = f2bf(hv);
        hall[(size_t)(t * 64 + b) * 512 + j] = hv;
    }
}

// ---------------- logits = hall @ out_w^T + out_b (MFMA bf16) ----------------
// reads only ws + original inputs; writes the whole of d_out
__global__ __launch_bounds__(256)
void gemm_logits_mfma(const float* __restrict__ outw, const float* __restrict__ outb,
                      const float* __restrict__ ws, float* __restrict__ out) {
    __shared__ unsigned short At[64 * 32];
    __shared__ unsigned short Bt[64 * 32];
    const float* hall = ws + OFF_HALL;
    const int tid = threadIdx.x;
    const int lane = tid & 63, wave = tid >> 6;
    const int wr = wave >> 1, wc = wave & 1;
    const int t = blockIdx.x;
    const int n0 = blockIdx.y * 64;
    const int srow = tid >> 2, skg = tid & 3;
    int brow = n0 + srow; if (brow > 9999) brow = 9999;
    const float* ga = hall + (size_t)(t * 64 + srow) * 512 + skg * 8;
    const float* gb = outw + (size_t)brow * 512 + skg * 8;
    const int ar0 = (wr * 32 + (lane & 15)) * 32 + (lane >> 4) * 8;
    const int br0 = (wc * 32 + (lane & 15)) * 32 + (lane >> 4) * 8;
    f32x4 acc[2][2] = {};
    for (int k0 = 0; k0 < 512; k0 += 32) {
        float4 a0 = *reinterpret_cast<const float4*>(ga + k0);
        float4 a1 = *reinterpret_cast<const float4*>(ga + k0 + 4);
        float4 b0 = *reinterpret_cast<const float4*>(gb + k0);
        float4 b1 = *reinterpret_cast<const float4*>(gb + k0 + 4);
        ushort8 ua, ub;
        ua[0]=f2bf(a0.x); ua[1]=f2bf(a0.y); ua[2]=f2bf(a0.z); ua[3]=f2bf(a0.w);
        ua[4]=f2bf(a1.x); ua[5]=f2bf(a1.y); ua[6]=f2bf(a1.z); ua[7]=f2bf(a1.w);
        ub[0]=f2bf(b0.x); ub[1]=f2bf(b0.y); ub[2]=f2bf(b0.z); ub[3]=f2bf(b0.w);
        ub[4]=f2bf(b1.x); ub[5]=f2bf(b1.y); ub[6]=f2bf(b1.z); ub[7]=f2bf(b1.w);
        *reinterpret_cast<ushort8*>(&At[tid * 8]) = ua;
        *reinterpret_cast<ushort8*>(&Bt[tid * 8]) = ub;
        __syncthreads();
        bf16x8 af0 = *reinterpret_cast<const bf16x8*>(&At[ar0]);
        bf16x8 af1 = *reinterpret_cast<const bf16x8*>(&At[ar0 + 16 * 32]);
        bf16x8 bf0 = *reinterpret_cast<const bf16x8*>(&Bt[br0]);
        bf16x8 bf1 = *reinterpret_cast<const bf16x8*>(&Bt[br0 + 16 * 32]);
        acc[0][0] = __builtin_amdgcn_mfma_f32_16x16x32_bf16(af0, bf0, acc[0][0], 0, 0, 0);
        acc[0][1] = __builtin_amdgcn_mfma_f32_16x16x32_bf16(af0, bf1, acc[0][1], 0, 0, 0);
        acc[1][0] = __builtin_amdgcn_mfma_f32_16x16x32_bf16(af1, bf0, acc[1][0], 0, 0, 0);
        acc[1][1] = __builtin_amdgcn_mfma_f32_16x16x32_bf16(af1, bf1, acc[1][1], 0, 0, 0);
        __syncthreads();
    }
#pragma unroll
    for (int fi = 0; fi < 2; ++fi)
#pragma unroll
        for (int fj = 0; fj < 2; ++fj)
#pragma unroll
            for (int r = 0; r < 4; ++r) {
                int b = wr * 32 + fi * 16 + (lane >> 4) * 4 + r;   // batch row
                int n = n0 + wc * 32 + fj * 16 + (lane & 15);
                if (n < 10000)
                    out[((size_t)b * 19 + t) * 10000 + n] = acc[fi][fj][r] + outb[n];
            }
}

extern "C" void kernel_launch(void* const* d_in, const int* in_sizes, int n_in,
                              void* d_out, int out_size, void* d_ws, size_t ws_size,
                              hipStream_t stream) {
    const float* V    = (const float*)d_in[0];
    const int*   caps = (const int*)d_in[1];
    const float* embW = (const float*)d_in[2];
    const float* Whw  = (const float*)d_in[3];
    const float* Whb  = (const float*)d_in[4];
    const float* Wvw  = (const float*)d_in[5];
    const float* Wvb  = (const float*)d_in[6];
    const float* vw   = (const float*)d_in[7];
    // d_in[8] = v_b: constant inside softmax -> cancels
    const float* Wih  = (const float*)d_in[9];
    const float* Whh  = (const float*)d_in[10];
    const float* bih  = (const float*)d_in[11];
    const float* bhh  = (const float*)d_in[12];
    const float* outw = (const float*)d_in[13];
    const float* outb = (const float*)d_in[14];
    float* ws  = (float*)d_ws;
    float* out = (float*)d_out;

    unsigned short* Wgh   = (unsigned short*)(out + D_WGH);
    float*          ge    = out + D_GE;
    unsigned short* kbuf  = (unsigned short*)(out + D_KB);
    unsigned short* Wvbf  = (unsigned short*)(out + D_WV);
    float*          part  = ws + OFF_PART;

    init_state<<<dim3(64), dim3(256), 0, stream>>>(ws);
    conv_wg<<<dim3(2560), dim3(256), 0, stream>>>(Wih, Whh, Wgh);
    conv_wv<<<dim3(512), dim3(256), 0, stream>>>(Wvw, Wvbf);
    gemm_k_mfma<<<dim3(196, 8), dim3(256), 0, stream>>>(V, Wvbf, Wvb, kbuf);
    emb_mfma<<<dim3(19, 32), dim3(256), 0, stream>>>(embW, caps, Wih, bih, bhh, ge);

    for (int t = 0; t < 19; ++t) {
        attn_fused<<<dim3(64), dim3(256), 0, stream>>>(Whw, Whb, vw, kbuf, ws);
        ctx_wide<<<dim3(8, 64), dim3(256), 0, stream>>>(V, ws);
        gates_mfma<<<dim3(32, 4), dim3(256), 0, stream>>>(ws, Wgh, part);
        lstm_step<<<dim3(64), dim3(256), 0, stream>>>(ws, ge, t);
    }

    gemm_logits_mfma<<<dim3(19, 157), dim3(256), 0, stream>>>(outw, outb, ws, out);
}